// Round 3
// baseline (336.554 us; speedup 1.0000x reference)
//
#include <hip/hip_runtime.h>

typedef __attribute__((ext_vector_type(8))) short short8v;
typedef __attribute__((ext_vector_type(4))) short short4v;
typedef __attribute__((ext_vector_type(4))) float float4v;
typedef __attribute__((ext_vector_type(4))) unsigned short ushort4v;
typedef __attribute__((ext_vector_type(8))) unsigned short ushort8v;

#define GLOBAL_AS __attribute__((address_space(1)))
#define LDS_AS __attribute__((address_space(3)))

__device__ __forceinline__ void async_cp16(const void* g, void* l) {
  __builtin_amdgcn_global_load_lds((const GLOBAL_AS void*)g, (LDS_AS void*)l, 16, 0, 0);
}

__device__ __forceinline__ unsigned short f2bf(float f) {
  unsigned u = __float_as_uint(f);
  u += 0x7fffu + ((u >> 16) & 1u);   // RNE to bf16
  return (unsigned short)(u >> 16);
}

// amdgcn target-builtins are invisible in the host pass — gate all probes.
#if defined(__HIP_DEVICE_COMPILE__)
#if __has_builtin(__builtin_amdgcn_exp2f)
#define EXP2F(x) __builtin_amdgcn_exp2f(x)
#else
#define EXP2F(x) exp2f(x)
#endif
#else
#define EXP2F(x) exp2f(x)
#endif

#if defined(__HIP_DEVICE_COMPILE__) && __has_builtin(__builtin_amdgcn_cvt_pk_bf16_f32)
typedef __attribute__((ext_vector_type(2))) __bf16 bf16x2v;
__device__ __forceinline__ unsigned pk_bf16(float a, float b) {
  bf16x2v r = __builtin_amdgcn_cvt_pk_bf16_f32(a, b);
  return __builtin_bit_cast(unsigned, r);
}
#else
__device__ __forceinline__ unsigned pk_bf16(float a, float b) {
  return (unsigned)f2bf(a) | ((unsigned)f2bf(b) << 16);
}
#endif

#define MFMA_QK(a, b, c) __builtin_amdgcn_mfma_f32_16x16x32_bf16(a, b, c, 0, 0, 0)

// Raw workgroup barrier with compiler memory fence (no implicit vmcnt(0)
// drain — that drain was the ~80% stall in the old single-step GEMMs).
__device__ __forceinline__ void wg_barrier() {
  asm volatile("" ::: "memory");
  __builtin_amdgcn_s_barrier();
  asm volatile("" ::: "memory");
}

// ---------------------------------------------------------------- converters

__global__ __launch_bounds__(256) void cvt_f32_bf16(const float* __restrict__ src,
                                                    unsigned short* __restrict__ dst) {
  int i = blockIdx.x * 256 + threadIdx.x;
  float4 v = ((const float4*)src)[i];
  ushort4v o;
  o.x = f2bf(v.x); o.y = f2bf(v.y); o.z = f2bf(v.z); o.w = f2bf(v.w);
  ((ushort4v*)dst)[i] = o;
}

// src: K x N fp32  ->  dst: N x K bf16 (transposed)
__global__ __launch_bounds__(256) void transpose_w(const float* __restrict__ src,
                                                   unsigned short* __restrict__ dst,
                                                   int K, int N) {
  __shared__ float tile[64][65];
  int k0 = blockIdx.x * 64, n0 = blockIdx.y * 64;
  int t = threadIdx.x;
  int tc = t & 15, tr = t >> 4;
#pragma unroll
  for (int p = 0; p < 4; p++) {
    int r = tr + p * 16;
    float4 v = *(const float4*)(src + (size_t)(k0 + r) * N + n0 + tc * 4);
    tile[r][tc * 4 + 0] = v.x; tile[r][tc * 4 + 1] = v.y;
    tile[r][tc * 4 + 2] = v.z; tile[r][tc * 4 + 3] = v.w;
  }
  __syncthreads();
#pragma unroll
  for (int p = 0; p < 4; p++) {
    int rn = tr + p * 16;
    ushort4v o;
    o.x = f2bf(tile[tc * 4 + 0][rn]);
    o.y = f2bf(tile[tc * 4 + 1][rn]);
    o.z = f2bf(tile[tc * 4 + 2][rn]);
    o.w = f2bf(tile[tc * 4 + 3][rn]);
    *(ushort4v*)(dst + (size_t)(n0 + rn) * K + k0 + tc * 4) = o;
  }
}

// ---------------------------------------------------------------- GEMM staging
// Swizzle (HW-verified 0 bank conflicts in R2): physical 16B slot s of row
// holds logical chunk s ^ ((row>>1)&3). global_load_lds dest stays linear;
// the GLOBAL source is pre-swizzled; ds_read applies the same XOR.

// 256 rows x 32 cols bf16, 512 threads, 2 cp16/thread.
__device__ __forceinline__ void stage256x32(const unsigned short* __restrict__ src,
                                            unsigned short* dst, int r0, int k0, int tid) {
#pragma unroll
  for (int p = 0; p < 2; p++) {
    int idx = p * 512 + tid;
    int row = idx >> 2, s = idx & 3;
    int ch = s ^ ((row >> 1) & 3);
    async_cp16(src + (size_t)(r0 + row) * 1024 + k0 + ch * 8, dst + idx * 8);
  }
}

// 128 rows x 32 cols bf16, 512 threads, 1 cp16/thread.
__device__ __forceinline__ void stage128x32(const unsigned short* __restrict__ src,
                                            unsigned short* dst, int r0, int k0, int tid) {
  int row = tid >> 2, s = tid & 3;
  int ch = s ^ ((row >> 1) & 3);
  async_cp16(src + (size_t)(r0 + row) * 1024 + k0 + ch * 8, dst + tid * 8);
}

// ---------------------------------------------------------------- QKV GEMM
// R11: 256x256 tile, BK=32, 8 waves (2M x 4N), 3 LDS buffers, counted vmcnt.
// Iteration t: reads buf t%3 (staged during t-2, certified at end of t-1),
// stages tile t+2 into buf (t+2)%3 — disjoint from the read buffer AND from
// tile t+1's landed data; first write to a buffer is barrier-ordered after
// its last read (provably race-free). Boundary wait is vmcnt(4): tile t+2's
// 4 loads stay in flight across the barrier (T4 — never drain to 0).
// Q is pre-scaled by 0.125*log2(e); V tokens pre-permuted per 32-group for
// the attention PV fragment (see attn_kernel).

__global__ __launch_bounds__(512, 2) void gemm_qkv(const unsigned short* __restrict__ A,
                                                   const unsigned short* __restrict__ BT,
                                                   const float* __restrict__ bias,
                                                   unsigned short* __restrict__ Qo,
                                                   unsigned short* __restrict__ Ko,
                                                   unsigned short* __restrict__ VTo) {
  __shared__ unsigned short As[3][256 * 32];
  __shared__ unsigned short Bs[3][256 * 32];
  int tid = threadIdx.x;
  int lane = tid & 63, w = tid >> 6, g = (lane >> 4) & 3, c = lane & 15;
  int wr = w >> 2, wc = w & 3;
  // bijective XCD swizzle: 384 blocks = 8 XCDs x 48
  int id = blockIdx.x;
  int swz = (id & 7) * 48 + (id >> 3);
  int m0 = (swz & 31) * 256, n0 = (swz >> 5) * 256;

  float4v acc[8][4] = {};
  short8v bf[4];

  // prologue: stage tiles 0 and 1
  stage256x32(A, &As[0][0], m0, 0, tid);
  stage256x32(BT, &Bs[0][0], n0, 0, tid);
  stage256x32(A, &As[1][0], m0, 32, tid);
  stage256x32(BT, &Bs[1][0], n0, 32, tid);
  asm volatile("s_waitcnt vmcnt(4)" ::: "memory");  // tile 0 landed; tile 1 in flight
  wg_barrier();

  int cb = 0;
  for (int t = 0; t < 32; ++t) {
    int nb = cb + 2; if (nb >= 3) nb -= 3;  // buffer of tile t+2
    const unsigned short* Ap = &As[cb][0];
    const unsigned short* Bp = &Bs[cb][0];

    // ---- phase 0: A-frags 0..3 + all B-frags; stage A(t+2)
    short8v af[4];
#pragma unroll
    for (int i = 0; i < 4; i++) {
      int r = wr * 128 + i * 16 + c;
      af[i] = *(const short8v*)(Ap + r * 32 + (g ^ ((r >> 1) & 3)) * 8);
    }
#pragma unroll
    for (int j = 0; j < 4; j++) {
      int r = wc * 64 + j * 16 + c;
      bf[j] = *(const short8v*)(Bp + r * 32 + (g ^ ((r >> 1) & 3)) * 8);
    }
    if (t + 2 < 32) stage256x32(A, &As[nb][0], m0, (t + 2) * 32, tid);
    wg_barrier();
    __builtin_amdgcn_s_setprio(1);
#pragma unroll
    for (int i = 0; i < 4; i++)
#pragma unroll
      for (int j = 0; j < 4; j++)
        acc[i][j] = MFMA_QK(af[i], bf[j], acc[i][j]);
    __builtin_amdgcn_s_setprio(0);
    wg_barrier();

    // ---- phase 1: A-frags 4..7; stage B(t+2); boundary vmcnt
#pragma unroll
    for (int i = 0; i < 4; i++) {
      int r = wr * 128 + 64 + i * 16 + c;
      af[i] = *(const short8v*)(Ap + r * 32 + (g ^ ((r >> 1) & 3)) * 8);
    }
    if (t + 2 < 32) stage256x32(BT, &Bs[nb][0], n0, (t + 2) * 32, tid);
    if (t < 30) { asm volatile("s_waitcnt vmcnt(4)" ::: "memory"); }
    else        { asm volatile("s_waitcnt vmcnt(0)" ::: "memory"); }
    wg_barrier();
    __builtin_amdgcn_s_setprio(1);
#pragma unroll
    for (int i = 0; i < 4; i++)
#pragma unroll
      for (int j = 0; j < 4; j++)
        acc[4 + i][j] = MFMA_QK(af[i], bf[j], acc[4 + i][j]);
    __builtin_amdgcn_s_setprio(0);
    wg_barrier();

    cb = cb + 1 == 3 ? 0 : cb + 1;
  }

  int which = n0 >> 10;  // 0=Q 1=K 2=V, uniform per block (n0 multiple of 256)
#pragma unroll
  for (int j = 0; j < 4; j++) {
    int ng = n0 + wc * 64 + j * 16 + c;
    float bv = bias[ng];
    int h = (ng & 1023) >> 6, d = ng & 63;
#pragma unroll
    for (int i = 0; i < 8; i++) {
#pragma unroll
      for (int r = 0; r < 4; r++) {
        int mg = m0 + wr * 128 + i * 16 + g * 4 + r;
        int b = mg >> 11, n = mg & 2047;
        float v = acc[i][j][r] + bv;
        if (which == 0)
          Qo[((size_t)(b * 16 + h) * 2048 + n) * 64 + d] = f2bf(v * 0.18033688011112042f);
        else if (which == 1)
          Ko[((size_t)(b * 16 + h) * 2048 + n) * 64 + d] = f2bf(v);
        else {
          // permute token within its 32-group: np = 8*((n>>2)&3)+4*((n>>4)&1)+(n&3)
          int np = (n & ~31) | (((n >> 2) & 3) << 3) | (((n >> 4) & 1) << 2) | (n & 3);
          VTo[((size_t)(b * 16 + h) * 64 + d) * 2048 + np] = f2bf(v);
        }
      }
    }
  }
}

// ---------------------------------------------------------------- attention
// R8: PV uses 16x16x32 MFMA via permuted-K (MFMA sums over k in any order).
// R9: each wave owns 64 Q-rows -> per-query K/V LDS reads halved; grid 512,
//     2 blocks/CU. V tokens pre-permuted in global so the PV B-fragment is
//     one ds_read_b128. s_setprio(1) wraps the MFMA clusters (T5).

#define NTOK 2048
#define BK 64

__global__ __launch_bounds__(256, 2) void attn_kernel(const unsigned short* __restrict__ Qg,
                                                      const unsigned short* __restrict__ Kg,
                                                      const unsigned short* __restrict__ VTg,
                                                      unsigned short* __restrict__ Og) {
  __shared__ unsigned short Ks[2][BK * 64];   // [buf][row][8 chunks, row-XOR swizzled]
  __shared__ unsigned short VTs[2][64 * BK];  // [buf][d][8 chunks, d-XOR swizzled]

  int tid = threadIdx.x;
  int lane = tid & 63, w = tid >> 6, g = lane >> 4, c = lane & 15;
  // XCD-locality swizzle: 512 blocks = 8 XCDs x (8 bh) x (8 q-chunks of 256)
  int id = blockIdx.x;
  int xcd = id & 7, within = id >> 3;
  int bh = xcd * 8 + (within >> 3);
  int q0 = (within & 7) * 256;

  const unsigned short* Qb = Qg + (size_t)bh * NTOK * 64;
  const unsigned short* Kb = Kg + (size_t)bh * NTOK * 64;
  const unsigned short* VTb = VTg + (size_t)bh * 64 * NTOK;

  // Q fragments straight from global (one-time; 16B/lane); 64 rows per wave
  short8v qf[4][2];
#pragma unroll
  for (int nt = 0; nt < 4; nt++)
#pragma unroll
    for (int kk = 0; kk < 2; kk++)
      qf[nt][kk] = *(const short8v*)(Qb + (size_t)(q0 + w * 64 + nt * 16 + c) * 64 +
                                     kk * 32 + g * 8);

  short8v ones8;
#pragma unroll
  for (int i = 0; i < 8; i++) ones8[i] = (short)0x3F80;

  float4v lacc[4] = {};
  float4v o[4][4] = {};

  // prologue: stage tile 0 into buf 0
#pragma unroll
  for (int p = 0; p < 2; p++) {
    int idx = p * 256 + tid;
    int row = idx >> 3, ch = idx & 7;
    async_cp16(Kb + (size_t)row * 64 + ((ch ^ (row & 7)) * 8), &Ks[0][idx * 8]);
    async_cp16(VTb + (size_t)row * NTOK + ((ch ^ (row & 7)) * 8), &VTs[0][idx * 8]);
  }

  for (int it = 0; it < NTOK / BK; it++) {
    int pb = it & 1;
    __syncthreads();  // drains own DMAs for tile it (issued a full phase ago)

    if (it + 1 < NTOK / BK) {
      int kt = (it + 1) * BK;
#pragma unroll
      for (int p = 0; p < 2; p++) {
        int idx = p * 256 + tid;
        int row = idx >> 3, ch = idx & 7;
        async_cp16(Kb + (size_t)(kt + row) * 64 + ((ch ^ (row & 7)) * 8),
                   &Ks[1 - pb][idx * 8]);
        async_cp16(VTb + (size_t)row * NTOK + kt + ((ch ^ (row & 7)) * 8),
                   &VTs[1 - pb][idx * 8]);
      }
    }

    const unsigned short* Kp = &Ks[pb][0];
    const unsigned short* Vp = &VTs[pb][0];

    // two key-chunk PAIRS (32 keys each): QK both chunks -> exp/pack into
    // one K=32 A-fragment -> PV + L at K=32
#pragma unroll
    for (int t = 0; t < 2; t++) {
      float4v st[2][4] = {};
      __builtin_amdgcn_s_setprio(1);
#pragma unroll
      for (int mth = 0; mth < 2; mth++) {
        int row = (t * 2 + mth) * 16 + c;
        short8v kf[2];
#pragma unroll
        for (int kk = 0; kk < 2; kk++) {
          int ch = (kk * 4 + g) ^ (row & 7);
          kf[kk] = *(const short8v*)(Kp + row * 64 + ch * 8);
        }
#pragma unroll
        for (int nt = 0; nt < 4; nt++)
#pragma unroll
          for (int kk = 0; kk < 2; kk++)
            st[mth][nt] = MFMA_QK(kf[kk], qf[nt][kk], st[mth][nt]);
      }
      __builtin_amdgcn_s_setprio(0);

      short8v pa8[4];
#pragma unroll
      for (int nt = 0; nt < 4; nt++) {
        float4v a = st[0][nt], b2 = st[1][nt];
        a.x = EXP2F(a.x); a.y = EXP2F(a.y); a.z = EXP2F(a.z); a.w = EXP2F(a.w);
        b2.x = EXP2F(b2.x); b2.y = EXP2F(b2.y); b2.z = EXP2F(b2.z); b2.w = EXP2F(b2.w);
        union { unsigned u[4]; short8v s; } cv;
        cv.u[0] = pk_bf16(a.x, a.y);
        cv.u[1] = pk_bf16(a.z, a.w);
        cv.u[2] = pk_bf16(b2.x, b2.y);
        cv.u[3] = pk_bf16(b2.z, b2.w);
        pa8[nt] = cv.s;
      }

      __builtin_amdgcn_s_setprio(1);
#pragma unroll
      for (int nt_o = 0; nt_o < 4; nt_o++) {
        int d = nt_o * 16 + c;
        int s = (t * 4 + g) ^ (d & 7);  // unit t*4+g holds the lane's 8 keys
        short8v vb8 = *(const short8v*)(Vp + d * BK + s * 8);
#pragma unroll
        for (int mt = 0; mt < 4; mt++)
          o[mt][nt_o] = MFMA_QK(pa8[mt], vb8, o[mt][nt_o]);
      }
#pragma unroll
      for (int mt = 0; mt < 4; mt++)
        lacc[mt] = MFMA_QK(pa8[mt], ones8, lacc[mt]);
      __builtin_amdgcn_s_setprio(0);
    }
  }

  // epilogue: lacc[mt][r] = L[q] in exactly o's row layout; no cross-lane
  int b = bh >> 4, h = bh & 15;
#pragma unroll
  for (int mt = 0; mt < 4; mt++) {
    float4v li;
#pragma unroll
    for (int r = 0; r < 4; r++) li[r] = 1.0f / lacc[mt][r];
#pragma unroll
    for (int nt_o = 0; nt_o < 4; nt_o++) {
      float4v v = o[mt][nt_o] * li;
      int col = h * 64 + nt_o * 16 + c;
      int rowbase = b * NTOK + q0 + w * 64 + mt * 16 + g * 4;
#pragma unroll
      for (int r = 0; r < 4; r++)
        Og[(size_t)(rowbase + r) * 1024 + col] = f2bf(v[r]);
    }
  }
}

// ---------------------------------------------------------------- proj GEMM
// R11: 128x256 tile (grid 64x4 = 256 blocks = exactly 1/CU), BK=32, 8 waves,
// same 3-buffer counted-vmcnt pipeline as gemm_qkv. Per tile: stage A (1
// cp16) in phase 0, B (2 cp16) in phase 1 -> boundary vmcnt(3).

__global__ __launch_bounds__(512, 2) void gemm_proj(const unsigned short* __restrict__ A,
                                                    const unsigned short* __restrict__ BT,
                                                    const float* __restrict__ bias,
                                                    float* __restrict__ out) {
  __shared__ unsigned short As[3][128 * 32];
  __shared__ unsigned short Bs[3][256 * 32];
  int tid = threadIdx.x;
  int lane = tid & 63, w = tid >> 6, g = (lane >> 4) & 3, c = lane & 15;
  int wr = w >> 2, wc = w & 3;
  int id = blockIdx.x;
  int swz = (id & 7) * 32 + (id >> 3);   // 256 = 8 x 32, bijective
  int m0 = (swz & 63) * 128, n0 = (swz >> 6) * 256;

  float4v acc[4][4] = {};
  short8v bf[4];

  stage128x32(A, &As[0][0], m0, 0, tid);
  stage256x32(BT, &Bs[0][0], n0, 0, tid);
  stage128x32(A, &As[1][0], m0, 32, tid);
  stage256x32(BT, &Bs[1][0], n0, 32, tid);
  asm volatile("s_waitcnt vmcnt(3)" ::: "memory");
  wg_barrier();

  int cb = 0;
  for (int t = 0; t < 32; ++t) {
    int nb = cb + 2; if (nb >= 3) nb -= 3;
    const unsigned short* Ap = &As[cb][0];
    const unsigned short* Bp = &Bs[cb][0];

    // ---- phase 0: A-frags 0..1 + all B-frags; stage A(t+2)
    short8v af[2];
#pragma unroll
    for (int i = 0; i < 2; i++) {
      int r = wr * 64 + i * 16 + c;
      af[i] = *(const short8v*)(Ap + r * 32 + (g ^ ((r >> 1) & 3)) * 8);
    }
#pragma unroll
    for (int j = 0; j < 4; j++) {
      int r = wc * 64 + j * 16 + c;
      bf[j] = *(const short8v*)(Bp + r * 32 + (g ^ ((r >> 1) & 3)) * 8);
    }
    if (t + 2 < 32) stage128x32(A, &As[nb][0], m0, (t + 2) * 32, tid);
    wg_barrier();
    __builtin_amdgcn_s_setprio(1);
#pragma unroll
    for (int i = 0; i < 2; i++)
#pragma unroll
      for (int j = 0; j < 4; j++)
        acc[i][j] = MFMA_QK(af[i], bf[j], acc[i][j]);
    __builtin_amdgcn_s_setprio(0);
    wg_barrier();

    // ---- phase 1: A-frags 2..3; stage B(t+2); boundary vmcnt
#pragma unroll
    for (int i = 0; i < 2; i++) {
      int r = wr * 64 + 32 + i * 16 + c;
      af[i] = *(const short8v*)(Ap + r * 32 + (g ^ ((r >> 1) & 3)) * 8);
    }
    if (t + 2 < 32) stage256x32(BT, &Bs[nb][0], n0, (t + 2) * 32, tid);
    if (t < 30) { asm volatile("s_waitcnt vmcnt(3)" ::: "memory"); }
    else        { asm volatile("s_waitcnt vmcnt(0)" ::: "memory"); }
    wg_barrier();
    __builtin_amdgcn_s_setprio(1);
#pragma unroll
    for (int i = 0; i < 2; i++)
#pragma unroll
      for (int j = 0; j < 4; j++)
        acc[2 + i][j] = MFMA_QK(af[i], bf[j], acc[2 + i][j]);
    __builtin_amdgcn_s_setprio(0);
    wg_barrier();

    cb = cb + 1 == 3 ? 0 : cb + 1;
  }

#pragma unroll
  for (int j = 0; j < 4; j++) {
    int ng = n0 + wc * 64 + j * 16 + c;
    float bv = bias[ng];
#pragma unroll
    for (int i = 0; i < 4; i++) {
#pragma unroll
      for (int r = 0; r < 4; r++) {
        int mg = m0 + wr * 64 + i * 16 + g * 4 + r;
        out[(size_t)mg * 1024 + ng] = acc[i][j][r] + bv;
      }
    }
  }
}

// ---------------------------------------------------------------- launch

extern "C" void kernel_launch(void* const* d_in, const int* in_sizes, int n_in,
                              void* d_out, int out_size, void* d_ws, size_t ws_size,
                              hipStream_t stream) {
  (void)in_sizes; (void)n_in; (void)out_size; (void)ws_size;
  const float* x = (const float*)d_in[0];
  const float* w_qkv = (const float*)d_in[1];
  const float* b_qkv = (const float*)d_in[2];
  const float* w_proj = (const float*)d_in[3];
  const float* b_proj = (const float*)d_in[4];
  float* out = (float*)d_out;

  unsigned short* x_bf = (unsigned short*)d_ws;          // 8192*1024
  unsigned short* wqkvT = x_bf + (size_t)8192 * 1024;    // 3072*1024
  unsigned short* wprojT = wqkvT + (size_t)3072 * 1024;  // 1024*1024
  unsigned short* qws = wprojT + (size_t)1024 * 1024;    // 64*2048*64
  unsigned short* kws = qws + (size_t)8388608;
  unsigned short* vtws = kws + (size_t)8388608;
  unsigned short* aws = vtws + (size_t)8388608;          // attn out 8192*1024

  cvt_f32_bf16<<<8192, 256, 0, stream>>>(x, x_bf);
  transpose_w<<<dim3(16, 48), 256, 0, stream>>>(w_qkv, wqkvT, 1024, 3072);
  transpose_w<<<dim3(16, 16), 256, 0, stream>>>(w_proj, wprojT, 1024, 1024);
  gemm_qkv<<<384, 512, 0, stream>>>(x_bf, wqkvT, b_qkv, qws, kws, vtws);
  attn_kernel<<<512, 256, 0, stream>>>(qws, kws, vtws, aws);
  gemm_proj<<<256, 512, 0, stream>>>(aws, wprojT, b_proj, out);
}

// Round 4
// 276.912 us; speedup vs baseline: 1.2154x; 1.2154x over previous
//
#include <hip/hip_runtime.h>

typedef __attribute__((ext_vector_type(8))) short short8v;
typedef __attribute__((ext_vector_type(4))) short short4v;
typedef __attribute__((ext_vector_type(4))) float float4v;
typedef __attribute__((ext_vector_type(4))) unsigned short ushort4v;
typedef __attribute__((ext_vector_type(8))) unsigned short ushort8v;

#define GLOBAL_AS __attribute__((address_space(1)))
#define LDS_AS __attribute__((address_space(3)))

__device__ __forceinline__ void async_cp16(const void* g, void* l) {
  __builtin_amdgcn_global_load_lds((const GLOBAL_AS void*)g, (LDS_AS void*)l, 16, 0, 0);
}

__device__ __forceinline__ unsigned short f2bf(float f) {
  unsigned u = __float_as_uint(f);
  u += 0x7fffu + ((u >> 16) & 1u);   // RNE to bf16
  return (unsigned short)(u >> 16);
}

// amdgcn target-builtins are invisible in the host pass — gate all probes.
#if defined(__HIP_DEVICE_COMPILE__)
#if __has_builtin(__builtin_amdgcn_exp2f)
#define EXP2F(x) __builtin_amdgcn_exp2f(x)
#else
#define EXP2F(x) exp2f(x)
#endif
#else
#define EXP2F(x) exp2f(x)
#endif

#if defined(__HIP_DEVICE_COMPILE__) && __has_builtin(__builtin_amdgcn_cvt_pk_bf16_f32)
typedef __attribute__((ext_vector_type(2))) __bf16 bf16x2v;
__device__ __forceinline__ unsigned pk_bf16(float a, float b) {
  bf16x2v r = __builtin_amdgcn_cvt_pk_bf16_f32(a, b);
  return __builtin_bit_cast(unsigned, r);
}
#else
__device__ __forceinline__ unsigned pk_bf16(float a, float b) {
  return (unsigned)f2bf(a) | ((unsigned)f2bf(b) << 16);
}
#endif

#define MFMA_QK(a, b, c) __builtin_amdgcn_mfma_f32_16x16x32_bf16(a, b, c, 0, 0, 0)

// ---------------------------------------------------------------- converters

__global__ __launch_bounds__(256) void cvt_f32_bf16(const float* __restrict__ src,
                                                    unsigned short* __restrict__ dst) {
  int i = blockIdx.x * 256 + threadIdx.x;
  float4 v = ((const float4*)src)[i];
  ushort4v o;
  o.x = f2bf(v.x); o.y = f2bf(v.y); o.z = f2bf(v.z); o.w = f2bf(v.w);
  ((ushort4v*)dst)[i] = o;
}

// src: K x N fp32  ->  dst: N x K bf16 (transposed)
__global__ __launch_bounds__(256) void transpose_w(const float* __restrict__ src,
                                                   unsigned short* __restrict__ dst,
                                                   int K, int N) {
  __shared__ float tile[64][65];
  int k0 = blockIdx.x * 64, n0 = blockIdx.y * 64;
  int t = threadIdx.x;
  int tc = t & 15, tr = t >> 4;
#pragma unroll
  for (int p = 0; p < 4; p++) {
    int r = tr + p * 16;
    float4 v = *(const float4*)(src + (size_t)(k0 + r) * N + n0 + tc * 4);
    tile[r][tc * 4 + 0] = v.x; tile[r][tc * 4 + 1] = v.y;
    tile[r][tc * 4 + 2] = v.z; tile[r][tc * 4 + 3] = v.w;
  }
  __syncthreads();
#pragma unroll
  for (int p = 0; p < 4; p++) {
    int rn = tr + p * 16;
    ushort4v o;
    o.x = f2bf(tile[tc * 4 + 0][rn]);
    o.y = f2bf(tile[tc * 4 + 1][rn]);
    o.z = f2bf(tile[tc * 4 + 2][rn]);
    o.w = f2bf(tile[tc * 4 + 3][rn]);
    *(ushort4v*)(dst + (size_t)(n0 + rn) * K + k0 + tc * 4) = o;
  }
}

// ---------------------------------------------------------------- GEMM staging
// Swizzle (HW-verified 0 bank conflicts in R2): physical 16B slot s of row
// holds logical chunk s ^ ((row>>1)&3). global_load_lds dest stays linear;
// the GLOBAL source is pre-swizzled; ds_read applies the same XOR.
// 128 rows x 32 cols bf16, 256 threads, 2 cp16/thread.
__device__ __forceinline__ void stage128x32(const unsigned short* __restrict__ src,
                                            unsigned short* dst, int r0, int k0, int tid) {
#pragma unroll
  for (int p = 0; p < 2; p++) {
    int idx = p * 256 + tid;
    int row = idx >> 2, s = idx & 3;
    int ch = s ^ ((row >> 1) & 3);
    async_cp16(src + (size_t)(r0 + row) * 1024 + k0 + ch * 8, dst + idx * 8);
  }
}

// ---------------------------------------------------------------- QKV GEMM
// R12: revert to the R1-proven loop (single-buffer, 2x syncthreads, 128x128,
// 256 threads, ~4 blocks/CU) — R2/R3 showed gemm_qkv is bound by the L2-miss
// memory path at ~1.1 TB/s (dur == hbm_bytes/1.1TB/s across 3 structures),
// so pipeline depth was never the lever. The lever is BYTES: the old VT
// epilogue scattered 2B stores at 4KB stride (partial-line RFO fills +
// double evictions: FETCH +24MB, WRITE 50 vs 24 ideal). V-blocks now
// transpose through LDS (aliased over the staging buffers, used only after
// the k-loop) and write VT as full 16B/lane contiguous ushort8 stores.
// Q is pre-scaled by 0.125*log2(e); V tokens pre-permuted per 32-group:
// position p within a 32-group holds token ((p>>2)&1)*16 + (p>>3)*4 + (p&3)
// (inverse of np = 8*((n>>2)&3)+4*((n>>4)&1)+(n&3)).

#define TT_STRIDE 136  // ushorts per tile_T row (272 B): breaks bank alignment

__global__ __launch_bounds__(256) void gemm_qkv(const unsigned short* __restrict__ A,
                                                const unsigned short* __restrict__ BT,
                                                const float* __restrict__ bias,
                                                unsigned short* __restrict__ Qo,
                                                unsigned short* __restrict__ Ko,
                                                unsigned short* __restrict__ VTo) {
  // staging (16 KB) and the V-transpose tile (34 KB) alias: tile_T is only
  // touched after the final k-loop barrier.
  __shared__ unsigned short smem[128 * TT_STRIDE];
  unsigned short* As = smem;          // 128*32
  unsigned short* Bs = smem + 4096;   // 128*32
  int tid = threadIdx.x;
  int lane = tid & 63, w = tid >> 6, g = lane >> 4, c = lane & 15;
  int m0 = blockIdx.x * 128, n0 = blockIdx.y * 128;
  int wm = (w & 1) * 64, wn = (w >> 1) * 64;
  float4v acc[4][4] = {};

  for (int k0 = 0; k0 < 1024; k0 += 32) {
    __syncthreads();
    stage128x32(A, As, m0, k0, tid);
    stage128x32(BT, Bs, n0, k0, tid);
    __syncthreads();
    short8v af[4], bf[4];
#pragma unroll
    for (int i = 0; i < 4; i++) {
      int r = wm + i * 16 + c;
      af[i] = *(const short8v*)(&As[r * 32 + (g ^ ((r >> 1) & 3)) * 8]);
    }
#pragma unroll
    for (int j = 0; j < 4; j++) {
      int r = wn + j * 16 + c;
      bf[j] = *(const short8v*)(&Bs[r * 32 + (g ^ ((r >> 1) & 3)) * 8]);
    }
#pragma unroll
    for (int i = 0; i < 4; i++)
#pragma unroll
      for (int j = 0; j < 4; j++)
        acc[i][j] = MFMA_QK(af[i], bf[j], acc[i][j]);
  }

  int which = n0 >> 10;  // 0=Q 1=K 2=V, uniform per block
  if (which != 2) {
    // Q/K: direct writes ([b,h,n,d], 32B chunks; adjacent j-stores merge in L2)
#pragma unroll
    for (int j = 0; j < 4; j++) {
      int ng = n0 + wn + j * 16 + c;
      float bv = bias[ng];
      int h = (ng & 1023) >> 6, d = ng & 63;
#pragma unroll
      for (int i = 0; i < 4; i++) {
#pragma unroll
        for (int r = 0; r < 4; r++) {
          int mg = m0 + wm + i * 16 + g * 4 + r;
          int b = mg >> 11, n = mg & 2047;
          float v = acc[i][j][r] + bv;
          if (which == 0)
            Qo[((size_t)(b * 16 + h) * 2048 + n) * 64 + d] = f2bf(v * 0.18033688011112042f);
          else
            Ko[((size_t)(b * 16 + h) * 2048 + n) * 64 + d] = f2bf(v);
        }
      }
    }
  } else {
    // V: transpose through LDS -> full-line n-major VT writes.
    __syncthreads();  // all staging reads done; safe to reuse smem as tile_T
#pragma unroll
    for (int j = 0; j < 4; j++) {
      int nl = wn + j * 16 + c;          // n_local = hl*64 + d
      float bv = bias[n0 + nl];
#pragma unroll
      for (int i = 0; i < 4; i++) {
        int ml = wm + i * 16 + g * 4;    // token_local (4 consecutive via r)
        unsigned p0 = pk_bf16(acc[i][j][0] + bv, acc[i][j][1] + bv);
        unsigned p1 = pk_bf16(acc[i][j][2] + bv, acc[i][j][3] + bv);
        *(unsigned*)(smem + nl * TT_STRIDE + ml) = p0;
        *(unsigned*)(smem + nl * TT_STRIDE + ml + 2) = p1;
      }
    }
    __syncthreads();
    // write phase: 16B/lane = permuted-octet gather (tokens P*4+0..3 and +16)
    int rr = lane >> 4, tc = lane & 15;
    int P = tc & 3, g32 = tc >> 2;
    int b = m0 >> 11, mloc = m0 & 2047;
    int h0 = (n0 & 1023) >> 6;
#pragma unroll
    for (int s = 0; s < 8; s++) {
      int row = w * 32 + s * 4 + rr;     // n_local
      int h = h0 + (row >> 6), d = row & 63;
      const unsigned short* bp = smem + row * TT_STRIDE + g32 * 32 + P * 4;
      union { unsigned long long q[2]; ushort8v v; } u;
      u.q[0] = *(const unsigned long long*)(bp);
      u.q[1] = *(const unsigned long long*)(bp + 16);
      size_t gaddr = ((size_t)(b * 16 + h) * 64 + d) * 2048 + mloc + g32 * 32 + P * 8;
      *(ushort8v*)(VTo + gaddr) = u.v;
    }
  }
}

// ---------------------------------------------------------------- attention
// R8: PV uses 16x16x32 MFMA via permuted-K (MFMA sums over k in any order).
// R9: each wave owns 64 Q-rows -> per-query K/V LDS reads halved; grid 512,
//     2 blocks/CU. V tokens pre-permuted in global so the PV B-fragment is
//     one ds_read_b128. s_setprio(1) wraps the MFMA clusters (T5).

#define NTOK 2048
#define BK 64

__global__ __launch_bounds__(256, 2) void attn_kernel(const unsigned short* __restrict__ Qg,
                                                      const unsigned short* __restrict__ Kg,
                                                      const unsigned short* __restrict__ VTg,
                                                      unsigned short* __restrict__ Og) {
  __shared__ unsigned short Ks[2][BK * 64];   // [buf][row][8 chunks, row-XOR swizzled]
  __shared__ unsigned short VTs[2][64 * BK];  // [buf][d][8 chunks, d-XOR swizzled]

  int tid = threadIdx.x;
  int lane = tid & 63, w = tid >> 6, g = lane >> 4, c = lane & 15;
  // XCD-locality swizzle: 512 blocks = 8 XCDs x (8 bh) x (8 q-chunks of 256)
  int id = blockIdx.x;
  int xcd = id & 7, within = id >> 3;
  int bh = xcd * 8 + (within >> 3);
  int q0 = (within & 7) * 256;

  const unsigned short* Qb = Qg + (size_t)bh * NTOK * 64;
  const unsigned short* Kb = Kg + (size_t)bh * NTOK * 64;
  const unsigned short* VTb = VTg + (size_t)bh * 64 * NTOK;

  // Q fragments straight from global (one-time; 16B/lane); 64 rows per wave
  short8v qf[4][2];
#pragma unroll
  for (int nt = 0; nt < 4; nt++)
#pragma unroll
    for (int kk = 0; kk < 2; kk++)
      qf[nt][kk] = *(const short8v*)(Qb + (size_t)(q0 + w * 64 + nt * 16 + c) * 64 +
                                     kk * 32 + g * 8);

  short8v ones8;
#pragma unroll
  for (int i = 0; i < 8; i++) ones8[i] = (short)0x3F80;

  float4v lacc[4] = {};
  float4v o[4][4] = {};

  // prologue: stage tile 0 into buf 0
#pragma unroll
  for (int p = 0; p < 2; p++) {
    int idx = p * 256 + tid;
    int row = idx >> 3, ch = idx & 7;
    async_cp16(Kb + (size_t)row * 64 + ((ch ^ (row & 7)) * 8), &Ks[0][idx * 8]);
    async_cp16(VTb + (size_t)row * NTOK + ((ch ^ (row & 7)) * 8), &VTs[0][idx * 8]);
  }

  for (int it = 0; it < NTOK / BK; it++) {
    int pb = it & 1;
    __syncthreads();  // drains own DMAs for tile it (issued a full phase ago)

    if (it + 1 < NTOK / BK) {
      int kt = (it + 1) * BK;
#pragma unroll
      for (int p = 0; p < 2; p++) {
        int idx = p * 256 + tid;
        int row = idx >> 3, ch = idx & 7;
        async_cp16(Kb + (size_t)(kt + row) * 64 + ((ch ^ (row & 7)) * 8),
                   &Ks[1 - pb][idx * 8]);
        async_cp16(VTb + (size_t)row * NTOK + kt + ((ch ^ (row & 7)) * 8),
                   &VTs[1 - pb][idx * 8]);
      }
    }

    const unsigned short* Kp = &Ks[pb][0];
    const unsigned short* Vp = &VTs[pb][0];

    // two key-chunk PAIRS (32 keys each): QK both chunks -> exp/pack into
    // one K=32 A-fragment -> PV + L at K=32
#pragma unroll
    for (int t = 0; t < 2; t++) {
      float4v st[2][4] = {};
      __builtin_amdgcn_s_setprio(1);
#pragma unroll
      for (int mth = 0; mth < 2; mth++) {
        int row = (t * 2 + mth) * 16 + c;
        short8v kf[2];
#pragma unroll
        for (int kk = 0; kk < 2; kk++) {
          int ch = (kk * 4 + g) ^ (row & 7);
          kf[kk] = *(const short8v*)(Kp + row * 64 + ch * 8);
        }
#pragma unroll
        for (int nt = 0; nt < 4; nt++)
#pragma unroll
          for (int kk = 0; kk < 2; kk++)
            st[mth][nt] = MFMA_QK(kf[kk], qf[nt][kk], st[mth][nt]);
      }
      __builtin_amdgcn_s_setprio(0);

      short8v pa8[4];
#pragma unroll
      for (int nt = 0; nt < 4; nt++) {
        float4v a = st[0][nt], b2 = st[1][nt];
        a.x = EXP2F(a.x); a.y = EXP2F(a.y); a.z = EXP2F(a.z); a.w = EXP2F(a.w);
        b2.x = EXP2F(b2.x); b2.y = EXP2F(b2.y); b2.z = EXP2F(b2.z); b2.w = EXP2F(b2.w);
        union { unsigned u[4]; short8v s; } cv;
        cv.u[0] = pk_bf16(a.x, a.y);
        cv.u[1] = pk_bf16(a.z, a.w);
        cv.u[2] = pk_bf16(b2.x, b2.y);
        cv.u[3] = pk_bf16(b2.z, b2.w);
        pa8[nt] = cv.s;
      }

      __builtin_amdgcn_s_setprio(1);
#pragma unroll
      for (int nt_o = 0; nt_o < 4; nt_o++) {
        int d = nt_o * 16 + c;
        int s = (t * 4 + g) ^ (d & 7);  // unit t*4+g holds the lane's 8 keys
        short8v vb8 = *(const short8v*)(Vp + d * BK + s * 8);
#pragma unroll
        for (int mt = 0; mt < 4; mt++)
          o[mt][nt_o] = MFMA_QK(pa8[mt], vb8, o[mt][nt_o]);
      }
#pragma unroll
      for (int mt = 0; mt < 4; mt++)
        lacc[mt] = MFMA_QK(pa8[mt], ones8, lacc[mt]);
      __builtin_amdgcn_s_setprio(0);
    }
  }

  // epilogue: lacc[mt][r] = L[q] in exactly o's row layout; no cross-lane
  int b = bh >> 4, h = bh & 15;
#pragma unroll
  for (int mt = 0; mt < 4; mt++) {
    float4v li;
#pragma unroll
    for (int r = 0; r < 4; r++) li[r] = 1.0f / lacc[mt][r];
#pragma unroll
    for (int nt_o = 0; nt_o < 4; nt_o++) {
      float4v v = o[mt][nt_o] * li;
      int col = h * 64 + nt_o * 16 + c;
      int rowbase = b * NTOK + q0 + w * 64 + mt * 16 + g * 4;
#pragma unroll
      for (int r = 0; r < 4; r++)
        Og[(size_t)(rowbase + r) * 1024 + col] = f2bf(v[r]);
    }
  }
}

// ---------------------------------------------------------------- proj GEMM
// R12: reverted to the R1-proven single-buffer loop (output f32 stores are
// already full 64B lines — no epilogue work needed).
__global__ __launch_bounds__(256) void gemm_proj(const unsigned short* __restrict__ A,
                                                 const unsigned short* __restrict__ BT,
                                                 const float* __restrict__ bias,
                                                 float* __restrict__ out) {
  __shared__ unsigned short As[128 * 32];
  __shared__ unsigned short Bs[128 * 32];
  int tid = threadIdx.x;
  int lane = tid & 63, w = tid >> 6, g = lane >> 4, c = lane & 15;
  int m0 = blockIdx.x * 128, n0 = blockIdx.y * 128;
  int wm = (w & 1) * 64, wn = (w >> 1) * 64;
  float4v acc[4][4] = {};

  for (int k0 = 0; k0 < 1024; k0 += 32) {
    __syncthreads();
    stage128x32(A, As, m0, k0, tid);
    stage128x32(BT, Bs, n0, k0, tid);
    __syncthreads();
    short8v af[4], bf[4];
#pragma unroll
    for (int i = 0; i < 4; i++) {
      int r = wm + i * 16 + c;
      af[i] = *(const short8v*)(&As[r * 32 + (g ^ ((r >> 1) & 3)) * 8]);
    }
#pragma unroll
    for (int j = 0; j < 4; j++) {
      int r = wn + j * 16 + c;
      bf[j] = *(const short8v*)(&Bs[r * 32 + (g ^ ((r >> 1) & 3)) * 8]);
    }
#pragma unroll
    for (int i = 0; i < 4; i++)
#pragma unroll
      for (int j = 0; j < 4; j++)
        acc[i][j] = MFMA_QK(af[i], bf[j], acc[i][j]);
  }

#pragma unroll
  for (int j = 0; j < 4; j++) {
    int ng = n0 + wn + j * 16 + c;
    float bv = bias[ng];
#pragma unroll
    for (int i = 0; i < 4; i++) {
#pragma unroll
      for (int r = 0; r < 4; r++) {
        int mg = m0 + wm + i * 16 + g * 4 + r;
        out[(size_t)mg * 1024 + ng] = acc[i][j][r] + bv;
      }
    }
  }
}

// ---------------------------------------------------------------- launch

extern "C" void kernel_launch(void* const* d_in, const int* in_sizes, int n_in,
                              void* d_out, int out_size, void* d_ws, size_t ws_size,
                              hipStream_t stream) {
  (void)in_sizes; (void)n_in; (void)out_size; (void)ws_size;
  const float* x = (const float*)d_in[0];
  const float* w_qkv = (const float*)d_in[1];
  const float* b_qkv = (const float*)d_in[2];
  const float* w_proj = (const float*)d_in[3];
  const float* b_proj = (const float*)d_in[4];
  float* out = (float*)d_out;

  unsigned short* x_bf = (unsigned short*)d_ws;          // 8192*1024
  unsigned short* wqkvT = x_bf + (size_t)8192 * 1024;    // 3072*1024
  unsigned short* wprojT = wqkvT + (size_t)3072 * 1024;  // 1024*1024
  unsigned short* qws = wprojT + (size_t)1024 * 1024;    // 64*2048*64
  unsigned short* kws = qws + (size_t)8388608;
  unsigned short* vtws = kws + (size_t)8388608;
  unsigned short* aws = vtws + (size_t)8388608;          // attn out 8192*1024

  cvt_f32_bf16<<<8192, 256, 0, stream>>>(x, x_bf);
  transpose_w<<<dim3(16, 48), 256, 0, stream>>>(w_qkv, wqkvT, 1024, 3072);
  transpose_w<<<dim3(16, 16), 256, 0, stream>>>(w_proj, wprojT, 1024, 1024);
  gemm_qkv<<<dim3(64, 24), 256, 0, stream>>>(x_bf, wqkvT, b_qkv, qws, kws, vtws);
  attn_kernel<<<512, 256, 0, stream>>>(qws, kws, vtws, aws);
  gemm_proj<<<dim3(64, 8), 256, 0, stream>>>(aws, wprojT, b_proj, out);
}